// Round 16
// baseline (948.290 us; speedup 1.0000x reference)
//
#include <hip/hip_runtime.h>

typedef __bf16 bf16_t;
typedef bf16_t bf16x8 __attribute__((ext_vector_type(8)));
typedef float f32x4 __attribute__((ext_vector_type(4)));
typedef unsigned short u16x4 __attribute__((ext_vector_type(4)));
typedef unsigned short u16x8 __attribute__((ext_vector_type(8)));
typedef float f32x4v __attribute__((ext_vector_type(4)));

#define NL 4

__device__ __forceinline__ float bf2f(unsigned short u){
  unsigned int x = ((unsigned int)u) << 16;
  return __builtin_bit_cast(float, x);
}
__device__ __forceinline__ unsigned short f2bf(float f){
  unsigned int u = __builtin_bit_cast(unsigned int, f);
  u += 0x7FFFu + ((u >> 16) & 1u);
  return (unsigned short)(u >> 16);
}
__device__ __forceinline__ void gload16(const void* g, void* l){
  __builtin_amdgcn_global_load_lds((const __attribute__((address_space(1))) unsigned int*)g,
                                   (__attribute__((address_space(3))) unsigned int*)l, 16, 0, 0);
}

// ------- fused f32->bf16 convert + 64x64 transpose (all 768x768 weight mats, z=16) ----
__global__ __launch_bounds__(256) void transpose_cvt16(const float* __restrict__ wq,
                                                       const float* __restrict__ wk,
                                                       const float* __restrict__ wv,
                                                       const float* __restrict__ wo,
                                                       unsigned short* __restrict__ wqkvT,
                                                       unsigned short* __restrict__ woT){
  __shared__ unsigned short tile[64][72];
  const int zi = blockIdx.z;
  const size_t W = (size_t)768 * 768;
  const float* src = (zi < 4 ? wq : zi < 8 ? wk : zi < 12 ? wv : wo) + (size_t)(zi & 3) * W;
  unsigned short* dst = (zi < 12 ? wqkvT + (size_t)zi * W : woT + (size_t)(zi - 12) * W);
  int tc0 = blockIdx.x * 64, tr0 = blockIdx.y * 64;
  int t = threadIdx.x;
  int r = t >> 2, cs = (t & 3) * 16;
  const float* s = src + (size_t)(tr0 + r) * 768 + tc0 + cs;
  #pragma unroll
  for (int j = 0; j < 16; j += 4){
    f32x4v v = *(const f32x4v*)(s + j);
    #pragma unroll
    for (int q = 0; q < 4; q++) tile[r][cs + j + q] = f2bf(v[q]);
  }
  __syncthreads();
  int n = t >> 2;
  unsigned short* d = dst + (size_t)(tc0 + n) * 768 + tr0 + cs;
  u16x8 o0, o1;
  #pragma unroll
  for (int j = 0; j < 8; j++){ o0[j] = tile[cs + j][n]; o1[j] = tile[cs + 8 + j][n]; }
  *(u16x8*)d       = o0;
  *(u16x8*)(d + 8) = o1;
}

// ------- generic convert+transpose for FF weights -------------------------------------
__global__ __launch_bounds__(256) void transpose_cvt(const float* __restrict__ src,
                                                     unsigned short* __restrict__ dst,
                                                     int R, int C){
  __shared__ unsigned short tile[64][72];
  size_t boff = (size_t)blockIdx.z * (size_t)R * (size_t)C;
  int tc0 = blockIdx.x * 64, tr0 = blockIdx.y * 64;
  int t = threadIdx.x;
  int r = t >> 2, cs = (t & 3) * 16;
  const float* s = src + boff + (size_t)(tr0 + r) * C + tc0 + cs;
  #pragma unroll
  for (int j = 0; j < 16; j += 4){
    f32x4v v = *(const f32x4v*)(s + j);
    #pragma unroll
    for (int q = 0; q < 4; q++) tile[r][cs + j + q] = f2bf(v[q]);
  }
  __syncthreads();
  int n = t >> 2;
  unsigned short* d = dst + boff + (size_t)(tc0 + n) * R + tr0 + cs;
  u16x8 o0, o1;
  #pragma unroll
  for (int j = 0; j < 8; j++){ o0[j] = tile[cs + j][n]; o1[j] = tile[cs + 8 + j][n]; }
  *(u16x8*)d       = o0;
  *(u16x8*)(d + 8) = o1;
}

// ------- GEMM core v5c: 128x128, BK=64, 2-buf (64 KB), reg-frags, STAGE under MFMA ----
// R13: 2-buf is sync-minimal; >64 KB LDS = 1 block/CU = proven loss.
// R15: no setprio (negative on lockstep GEMM, m190).
// R16: optional residual add in epilogue (RESID) — moves a 12.6 MB read out of the
// BW-bound LN kernel into the stall-bound GEMM epilogue (~free under stall shadow).
template<int ACT, int STORE_MODE, int RESID>
__device__ __forceinline__ void gemm_core(unsigned short* lds,
                                          const unsigned short* __restrict__ A,
                                          const unsigned short* __restrict__ BT,
                                          const float* __restrict__ bias,
                                          unsigned short* __restrict__ C,
                                          const unsigned short* __restrict__ RES,
                                          int m0, int n0, int N, int K){
  const int t = threadIdx.x;
  const int lane = t & 63;
  const int l15 = lane & 15, l4 = lane >> 4;
  const int w = t >> 6, wm = w >> 1, wn = w & 1;
  f32x4 acc[4][4] = {};
  const int rr = t >> 3;
  const int c8 = ((t & 7) ^ (rr & 7)) * 8;
  const unsigned short* Abase = A  + (size_t)(m0 + rr) * K + c8;
  const unsigned short* Bbase = BT + (size_t)(n0 + rr) * K + c8;

  auto STAGE = [&](int k0, int buf){
    unsigned short* As_ = lds + buf * 16384;
    unsigned short* Bs_ = As_ + 8192;
    #pragma unroll
    for (int it = 0; it < 4; it++){
      gload16(Abase + (size_t)(it * 32) * K + k0, As_ + (it * 256 + t) * 8);
      gload16(Bbase + (size_t)(it * 32) * K + k0, Bs_ + (it * 256 + t) * 8);
    }
  };

  bf16x8 af[2][4], bfr[2][4];
  auto LOADFRAGS = [&](int buf){
    const unsigned short* Ab = lds + buf * 16384;
    const unsigned short* Bb = Ab + 8192;
    #pragma unroll
    for (int kk = 0; kk < 2; kk++){
      #pragma unroll
      for (int i = 0; i < 4; i++){
        const int so = ((kk * 4 + l4) ^ (l15 & 7)) * 8;
        af[kk][i]  = *(const bf16x8*)(Ab + (wm * 64 + i * 16 + l15) * 64 + so);
        bfr[kk][i] = *(const bf16x8*)(Bb + (wn * 64 + i * 16 + l15) * 64 + so);
      }
    }
  };
  auto MFMAS = [&](){
    #pragma unroll
    for (int kk = 0; kk < 2; kk++)
      #pragma unroll
      for (int j = 0; j < 4; j++)
        #pragma unroll
        for (int i = 0; i < 4; i++)
          acc[j][i] = __builtin_amdgcn_mfma_f32_16x16x32_bf16(bfr[kk][j], af[kk][i], acc[j][i], 0, 0, 0);
  };

  const int S = K >> 6;
  STAGE(0, 0); STAGE(64, 1);
  asm volatile("s_waitcnt vmcnt(8)" ::: "memory");
  __builtin_amdgcn_s_barrier();
  int cur = 0;
  for (int k = 0; k < S; k++){
    LOADFRAGS(cur);
    asm volatile("s_waitcnt lgkmcnt(0)" ::: "memory");
    __builtin_amdgcn_sched_barrier(0);         // rule #18: pin MFMA below the lgkm wait
    __builtin_amdgcn_s_barrier();              // all waves' frags in regs -> cur free
    if (k + 2 < S) STAGE((k + 2) << 6, cur);   // overwrite cur under the MFMAs
    MFMAS();
    if (k + 1 < S){
      if (k + 2 < S) asm volatile("s_waitcnt vmcnt(8)" ::: "memory");
      else           asm volatile("s_waitcnt vmcnt(0)" ::: "memory");
      __builtin_amdgcn_s_barrier();            // buf cur^1 staged for all waves
    }
    cur ^= 1;
  }

  const int mB = m0 + wm * 64;
  const int nB = n0 + wn * 64;
  if (STORE_MODE == 0){
    #pragma unroll
    for (int i = 0; i < 4; i++){
      unsigned short* crow = C + (size_t)(mB + i * 16 + l15) * N + nB;
      const unsigned short* rrow = RESID ? RES + (size_t)(mB + i * 16 + l15) * N + nB : nullptr;
      #pragma unroll
      for (int j = 0; j < 4; j++){
        const int nn = j * 16 + l4 * 4;
        f32x4v bb = *(const f32x4v*)(bias + nB + nn);
        u16x4 rv;
        if (RESID) rv = *(const u16x4*)(rrow + nn);
        u16x4 pk;
        #pragma unroll
        for (int r = 0; r < 4; r++){
          float v = acc[j][i][r] + bb[r];
          if (ACT == 1){
            float e = __expf(-1.5957691216057308f * (v + 0.044715f * v * v * v));
            v = __fdividef(v, 1.0f + e);
          }
          if (RESID) v += bf2f(rv[r]);
          pk[r] = f2bf(v);
        }
        *(u16x4*)(crow + nn) = pk;
      }
    }
  } else {
    // V^T store: dst[(m>>12)*768*4096 + n*4096 + (m&4095)]
    #pragma unroll
    for (int i = 0; i < 4; i++){
      const int m = mB + i * 16 + l15;
      unsigned short* vbase = C + (size_t)(m >> 12) * 768 * 4096 + (m & 4095);
      #pragma unroll
      for (int j = 0; j < 4; j++){
        const int nn = nB + j * 16 + l4 * 4;
        f32x4v bb = *(const f32x4v*)(bias + nn);
        #pragma unroll
        for (int r = 0; r < 4; r++)
          vbase[(size_t)(nn + r) * 4096] = f2bf(acc[j][i][r] + bb[r]);
      }
    }
  }
}

// grid = 8 XCDs x 8 m-chunk x Nn (1D). XCD x owns m in [x*8, x*8+8) for ALL n.
template<int ACT, int RESID>
__global__ __launch_bounds__(256) void gemm_bt(const unsigned short* __restrict__ A,
                                               const unsigned short* __restrict__ BT,
                                               const float* __restrict__ bias,
                                               unsigned short* __restrict__ C, int N, int K,
                                               const unsigned short* __restrict__ RES){
  __shared__ unsigned short lds[32768];
  const int b = blockIdx.x;
  const int s = b >> 3;
  const int m = (b & 7) * 8 + (s & 7);
  const int n = s >> 3;
  gemm_core<ACT, 0, RESID>(lds, A, BT, bias, C, RES, m * 128, n * 128, N, K);
}

// fused Q/K/V projection: 1152 blocks = 8 xcd x 8 m x 18; V written transposed to vt
__global__ __launch_bounds__(256) void qkv_gemm(const unsigned short* __restrict__ A,
                                                const unsigned short* __restrict__ wT,
                                                int l,
                                                const float* __restrict__ bq,
                                                const float* __restrict__ bk,
                                                const float* __restrict__ bv,
                                                unsigned short* __restrict__ q,
                                                unsigned short* __restrict__ k,
                                                unsigned short* __restrict__ vt){
  __shared__ unsigned short lds[32768];
  const int b = blockIdx.x;
  const int s = b >> 3;
  const int m0 = ((b & 7) * 8 + (s & 7)) * 128;
  const int grp = s >> 3;
  const int sel = grp / 6, col = grp % 6;
  const unsigned short* BT = wT + ((size_t)sel * NL + l) * (size_t)(768 * 768);
  if (sel == 2)      gemm_core<0, 2, 0>(lds, A, BT, bv, vt, nullptr, m0, col * 128, 768, 768);
  else               gemm_core<0, 0, 0>(lds, A, BT, sel == 0 ? bq : bk, sel == 0 ? q : k,
                                        nullptr, m0, col * 128, 768, 768);
}

// ---------------- sliding-window attention: dbuf K/V, stage-at-top, 1 barrier/chunk ---
__global__ __launch_bounds__(256, 4) void attn_kernel(const unsigned short* __restrict__ Q,
                                                      const unsigned short* __restrict__ Km,
                                                      const unsigned short* __restrict__ VT,
                                                      const int* __restrict__ mask1,
                                                      const int* __restrict__ mask2,
                                                      unsigned short* __restrict__ O){
  const int qt = blockIdx.x, h = blockIdx.y, seq = blockIdx.z;
  const int t = threadIdx.x, lane = t & 63, w = t >> 6;
  const int l15 = lane & 15, l4 = lane >> 4;
  __shared__ unsigned short Kc[2][64 * 64];
  __shared__ unsigned short VTc[2][64 * 64];
  __shared__ unsigned short Ps[4][16 * 64];
  const unsigned short* Qp  = Q  + (size_t)seq * 4096 * 768;
  const unsigned short* Kp  = Km + (size_t)seq * 4096 * 768;
  const unsigned short* VTp = VT + (size_t)seq * 768 * 4096;
  const int* mask = seq ? mask2 : mask1;
  unsigned short* Op = O + (size_t)seq * 4096 * 768;

  const int q0 = qt * 64 + w * 16;
  const int qg = q0 + l15;
  const int swz = (l15 & 7) * 8;

  bf16x8 qf[2];
  #pragma unroll
  for (int ks = 0; ks < 2; ks++)
    qf[ks] = *(const bf16x8*)(Qp + (size_t)qg * 768 + h * 64 + ks * 32 + l4 * 8);

  f32x4 oacc[4] = {};
  float rm = -1e30f, rl = 0.0f;

  const int kstart = qt * 64 >= 256 ? qt * 64 - 256 : 0;
  const int kend0  = qt * 64 + 320;
  const int kend   = kend0 > 4096 ? 4096 : kend0;
  const int nch    = (kend - kstart) >> 6;
  unsigned short* psw = &Ps[w][0];

  const int rr = t >> 3;
  const int c8 = (((t & 7) ^ (rr & 7)) * 8);

  auto STAGE = [&](int kb, int buf){
    gload16(Kp  + (size_t)(kb + rr) * 768 + h * 64 + c8,       Kc[buf] + t * 8);
    gload16(Kp  + (size_t)(kb + 32 + rr) * 768 + h * 64 + c8,  Kc[buf] + 2048 + t * 8);
    gload16(VTp + (size_t)(h * 64 + rr) * 4096 + kb + c8,      VTc[buf] + t * 8);
    gload16(VTp + (size_t)(h * 64 + 32 + rr) * 4096 + kb + c8, VTc[buf] + 2048 + t * 8);
  };

  STAGE(kstart, 0);
  asm volatile("s_waitcnt vmcnt(0)" ::: "memory");
  __builtin_amdgcn_s_barrier();
  int cur = 0;
  for (int ci = 0; ci < nch; ci++){
    const int kb = kstart + (ci << 6);
    if (ci + 1 < nch) STAGE(kb + 64, cur ^ 1);      // prefetch under compute
    if (kb + 63 >= q0 - 256 && kb <= q0 + 271){
      f32x4 sT[4];
      #pragma unroll
      for (int mt = 0; mt < 4; mt++){
        const unsigned short* kr = Kc[cur] + (mt * 16 + l15) * 64;
        bf16x8 kf0 = *(const bf16x8*)(kr + ((l4 * 8) ^ swz));
        bf16x8 kf1 = *(const bf16x8*)(kr + ((32 + l4 * 8) ^ swz));
        f32x4 z = {};
        z      = __builtin_amdgcn_mfma_f32_16x16x32_bf16(kf0, qf[0], z, 0, 0, 0);
        sT[mt] = __builtin_amdgcn_mfma_f32_16x16x32_bf16(kf1, qf[1], z, 0, 0, 0);
      }
      float smax = -1e30f;
      #pragma unroll
      for (int mt = 0; mt < 4; mt++){
        int4 mv = *(const int4*)(mask + kb + mt * 16 + l4 * 4);
        #pragma unroll
        for (int r = 0; r < 4; r++){
          int kgl = kb + mt * 16 + l4 * 4 + r;
          int d = kgl - qg;
          int mvv = (r == 0) ? mv.x : (r == 1) ? mv.y : (r == 2) ? mv.z : mv.w;
          bool ok = (mvv != 0) && (d <= 256) && (d >= -256);
          float v = sT[mt][r] * 0.125f;
          sT[mt][r] = ok ? v : -1e30f;
          smax = fmaxf(smax, sT[mt][r]);
        }
      }
      smax = fmaxf(smax, __shfl_xor(smax, 16, 64));
      smax = fmaxf(smax, __shfl_xor(smax, 32, 64));
      float nm = fmaxf(rm, smax);
      float sc = __expf(rm - nm);
      rm = nm;
      float psum = 0.0f;
      #pragma unroll
      for (int mt = 0; mt < 4; mt++){
        u16x4 pk;
        #pragma unroll
        for (int r = 0; r < 4; r++){
          float p = (sT[mt][r] > -1e29f) ? __expf(sT[mt][r] - nm) : 0.0f;
          psum += p;
          pk[r] = f2bf(p);
        }
        *(u16x4*)(psw + l15 * 64 + ((mt * 16 + l4 * 4) ^ swz)) = pk;
      }
      psum += __shfl_xor(psum, 16, 64);
      psum += __shfl_xor(psum, 32, 64);
      rl = rl * sc + psum;
      float scq[4];
      #pragma unroll
      for (int r = 0; r < 4; r++) scq[r] = __shfl(sc, l4 * 4 + r, 64);
      #pragma unroll
      for (int g = 0; g < 4; g++)
        #pragma unroll
        for (int r = 0; r < 4; r++) oacc[g][r] *= scq[r];
      asm volatile("s_waitcnt lgkmcnt(0)" ::: "memory");
      __builtin_amdgcn_sched_barrier(0);
      bf16x8 pa0 = *(const bf16x8*)(psw + l15 * 64 + ((l4 * 8) ^ swz));
      bf16x8 pa1 = *(const bf16x8*)(psw + l15 * 64 + ((32 + l4 * 8) ^ swz));
      #pragma unroll
      for (int g = 0; g < 4; g++){
        const unsigned short* vr = VTc[cur] + (g * 16 + l15) * 64;
        bf16x8 vb0 = *(const bf16x8*)(vr + ((l4 * 8) ^ swz));
        bf16x8 vb1 = *(const bf16x8*)(vr + ((32 + l4 * 8) ^ swz));
        oacc[g] = __builtin_amdgcn_mfma_f32_16x16x32_bf16(pa0, vb0, oacc[g], 0, 0, 0);
        oacc[g] = __builtin_amdgcn_mfma_f32_16x16x32_bf16(pa1, vb1, oacc[g], 0, 0, 0);
      }
    }
    asm volatile("s_waitcnt vmcnt(0)" ::: "memory");   // next chunk staged
    __builtin_amdgcn_s_barrier();                      // single barrier per chunk
    cur ^= 1;
  }
  float rlq[4];
  #pragma unroll
  for (int r = 0; r < 4; r++) rlq[r] = __shfl(rl, l4 * 4 + r, 64);
  #pragma unroll
  for (int g = 0; g < 4; g++)
    #pragma unroll
    for (int r = 0; r < 4; r++){
      float v = oacc[g][r] / rlq[r];
      Op[(size_t)(q0 + l4 * 4 + r) * 768 + h * 64 + g * 16 + l15] = f2bf(v);
    }
}

// ---------------- embed + LN (f32 tables -> bf16 out) --------------------------------
__global__ __launch_bounds__(192) void embed_ln(const int* __restrict__ ids1,
                                                const int* __restrict__ ids2,
                                                const float* __restrict__ we,
                                                const float* __restrict__ pe,
                                                const float* __restrict__ g,
                                                const float* __restrict__ b,
                                                unsigned short* __restrict__ out){
  const int row = blockIdx.x;
  const int seq = row >> 12, s = row & 4095;
  const int t = threadIdx.x;
  const int id = (seq ? ids2 : ids1)[s];
  f32x4v wvv = *(const f32x4v*)(we + (size_t)id * 768 + t * 4);
  f32x4v pv  = *(const f32x4v*)(pe + (size_t)s * 768 + t * 4);
  float v[4];
  #pragma unroll
  for (int j = 0; j < 4; j++) v[j] = wvv[j] + pv[j];
  float sum = 0, ss = 0;
  #pragma unroll
  for (int j = 0; j < 4; j++){ sum += v[j]; ss += v[j] * v[j]; }
  for (int off = 1; off < 64; off <<= 1){ sum += __shfl_xor(sum, off, 64); ss += __shfl_xor(ss, off, 64); }
  __shared__ float red[2][3];
  int wid = t >> 6;
  if ((t & 63) == 0){ red[0][wid] = sum; red[1][wid] = ss; }
  __syncthreads();
  sum = red[0][0] + red[0][1] + red[0][2];
  ss  = red[1][0] + red[1][1] + red[1][2];
  float mean = sum * (1.0f / 768.0f);
  float var  = ss * (1.0f / 768.0f) - mean * mean;
  float rstd = rsqrtf(var + 1e-5f);
  f32x4v gv = *(const f32x4v*)(g + t * 4);
  f32x4v bv = *(const f32x4v*)(b + t * 4);
  u16x4 o;
  #pragma unroll
  for (int j = 0; j < 4; j++) o[j] = f2bf((v[j] - mean) * rstd * gv[j] + bv[j]);
  *(u16x4*)(out + (size_t)row * 768 + t * 4) = o;
}

// ---------------- single-input LayerNorm (residual pre-added in GEMM epilogue) --------
__global__ __launch_bounds__(192) void ln_one(const unsigned short* __restrict__ X,
                                              const float* __restrict__ g,
                                              const float* __restrict__ b,
                                              unsigned short* __restrict__ out){
  const int row = blockIdx.x;
  const int t = threadIdx.x;
  u16x4 a4 = *(const u16x4*)(X + (size_t)row * 768 + t * 4);
  float v[4];
  #pragma unroll
  for (int j = 0; j < 4; j++) v[j] = bf2f(a4[j]);
  float sum = 0, ss = 0;
  #pragma unroll
  for (int j = 0; j < 4; j++){ sum += v[j]; ss += v[j] * v[j]; }
  for (int off = 1; off < 64; off <<= 1){ sum += __shfl_xor(sum, off, 64); ss += __shfl_xor(ss, off, 64); }
  __shared__ float red[2][3];
  int wid = t >> 6;
  if ((t & 63) == 0){ red[0][wid] = sum; red[1][wid] = ss; }
  __syncthreads();
  sum = red[0][0] + red[0][1] + red[0][2];
  ss  = red[1][0] + red[1][1] + red[1][2];
  float mean = sum * (1.0f / 768.0f);
  float var  = ss * (1.0f / 768.0f) - mean * mean;
  float rstd = rsqrtf(var + 1e-5f);
  f32x4v gv = *(const f32x4v*)(g + t * 4);
  f32x4v bv = *(const f32x4v*)(b + t * 4);
  u16x4 o;
  #pragma unroll
  for (int j = 0; j < 4; j++) o[j] = f2bf((v[j] - mean) * rstd * gv[j] + bv[j]);
  *(u16x4*)(out + (size_t)row * 768 + t * 4) = o;
}

// ---------------- column sums ---------------------------------------------------------
__global__ __launch_bounds__(256) void colmean(const unsigned short* __restrict__ X,
                                               float* __restrict__ mean){
  const int t = threadIdx.x;
  const int seq = blockIdx.y;
  const int r0 = blockIdx.x * 64;
  const unsigned short* base = X + ((size_t)seq * 4096 + r0) * 768;
  float a0 = 0, a1 = 0, a2 = 0;
  for (int r = 0; r < 64; r++){
    const unsigned short* p = base + (size_t)r * 768;
    a0 += bf2f(p[t]);
    a1 += bf2f(p[t + 256]);
    a2 += bf2f(p[t + 512]);
  }
  atomicAdd(&mean[seq * 768 + t], a0);
  atomicAdd(&mean[seq * 768 + t + 256], a1);
  atomicAdd(&mean[seq * 768 + t + 512], a2);
}

// ---------------- final dot + sigmoid (f32 out) ---------------------------------------
__global__ __launch_bounds__(256) void final_k(const float* __restrict__ means,
                                               const float* __restrict__ dw,
                                               const float* __restrict__ db,
                                               float* __restrict__ out){
  const int t = threadIdx.x;
  float part = 0;
  for (int c = t; c < 768; c += 256)
    part += (means[c] - means[768 + c]) * (1.0f / 4096.0f) * dw[c];
  for (int off = 1; off < 64; off <<= 1) part += __shfl_xor(part, off, 64);
  __shared__ float red[4];
  if ((t & 63) == 0) red[t >> 6] = part;
  __syncthreads();
  if (t == 0){
    float r = red[0] + red[1] + red[2] + red[3] + db[0];
    out[0] = 1.0f / (1.0f + expf(-r));
  }
}

// sentinel: written when workspace is too small, to make that failure diagnosable
__global__ void sentinel_k(float* out){ out[0] = -1.0f; }

extern "C" void kernel_launch(void* const* d_in, const int* in_sizes, int n_in,
                              void* d_out, int out_size, void* d_ws, size_t ws_size,
                              hipStream_t stream){
  (void)in_sizes; (void)n_in; (void)out_size;
  const int* ids1  = (const int*)d_in[0];
  const int* ids2  = (const int*)d_in[1];
  const int* mask1 = (const int*)d_in[2];
  const int* mask2 = (const int*)d_in[3];
  const float* we = (const float*)d_in[4];
  const float* pe = (const float*)d_in[5];
  const float* eg = (const float*)d_in[6];
  const float* eb = (const float*)d_in[7];
  const float* wq = (const float*)d_in[8];
  const float* bq = (const float*)d_in[9];
  const float* wk = (const float*)d_in[10];
  const float* bk = (const float*)d_in[11];
  const float* wv = (const float*)d_in[12];
  const float* bv = (const float*)d_in[13];
  const float* wo = (const float*)d_in[14];
  const float* bo = (const float*)d_in[15];
  const float* g1 = (const float*)d_in[16];
  const float* b1 = (const float*)d_in[17];
  const float* w1 = (const float*)d_in[18];
  const float* c1 = (const float*)d_in[19];
  const float* w2 = (const float*)d_in[20];
  const float* c2 = (const float*)d_in[21];
  const float* g2 = (const float*)d_in[22];
  const float* b2 = (const float*)d_in[23];
  const float* dw = (const float*)d_in[24];
  const float* db = (const float*)d_in[25];
  float* outp = (float*)d_out;

  char* ws = (char*)d_ws;
  size_t off = 0;
  auto alloc = [&](size_t bytes) -> char* {
    char* p = ws + off;
    off += (bytes + 255) & ~(size_t)255;
    return p;
  };
  const size_t W768 = (size_t)768 * 768;
  const size_t WFF  = (size_t)768 * 3072;
  unsigned short* wqkvT = (unsigned short*)alloc(3 * NL * W768 * 2);
  unsigned short* woT   = (unsigned short*)alloc(NL * W768 * 2);
  unsigned short* w1T   = (unsigned short*)alloc(NL * WFF * 2);
  unsigned short* w2T   = (unsigned short*)alloc(NL * WFF * 2);
  unsigned short* xb    = (unsigned short*)alloc((size_t)8192 * 768 * 2);
  unsigned short* qb_   = (unsigned short*)alloc((size_t)8192 * 768 * 2);
  unsigned short* kb_   = (unsigned short*)alloc((size_t)8192 * 768 * 2);
  unsigned short* vb_   = (unsigned short*)alloc((size_t)8192 * 768 * 2);
  unsigned short* hb    = (unsigned short*)alloc((size_t)8192 * 3072 * 2);
  unsigned short* vt    = (unsigned short*)alloc((size_t)2 * 768 * 4096 * 2);
  float* means          = (float*)alloc(2 * 768 * 4);
  if (off > ws_size){ sentinel_k<<<1, 1, 0, stream>>>(outp); return; }

  transpose_cvt16<<<dim3(12, 12, 16), 256, 0, stream>>>(wq, wk, wv, wo, wqkvT, woT);
  transpose_cvt<<<dim3(48, 12, NL), 256, 0, stream>>>(w1, w1T, 768, 3072);
  transpose_cvt<<<dim3(12, 48, NL), 256, 0, stream>>>(w2, w2T, 3072, 768);

  embed_ln<<<8192, 192, 0, stream>>>(ids1, ids2, we, pe, eg, eb, xb);

  for (int l = 0; l < NL; l++){
    qkv_gemm<<<1152, 256, 0, stream>>>(xb, wqkvT, l, bq + l * 768, bk + l * 768, bv + l * 768,
                                       qb_, kb_, vt);
    attn_kernel<<<dim3(64, 12, 2), 256, 0, stream>>>(qb_, kb_, vt, mask1, mask2, vb_);
    // proj with fused residual: qb_ = attn@Wo + bo + xb
    gemm_bt<0, 1><<<384, 256, 0, stream>>>(vb_, woT + (size_t)l * W768, bo + l * 768, qb_, 768, 768, xb);
    ln_one<<<8192, 192, 0, stream>>>(qb_, g1 + l * 768, b1 + l * 768, kb_);
    gemm_bt<1, 0><<<1536, 256, 0, stream>>>(kb_, w1T + (size_t)l * WFF, c1 + l * 3072, hb, 3072, 768, nullptr);
    // FF2 with fused residual: vb_ = h@W2 + c2 + kb_
    gemm_bt<0, 1><<<384, 256, 0, stream>>>(hb, w2T + (size_t)l * WFF, c2 + l * 768, vb_, 768, 3072, kb_);
    ln_one<<<8192, 192, 0, stream>>>(vb_, g2 + l * 768, b2 + l * 768, xb);
  }

  hipMemsetAsync(means, 0, 2 * 768 * 4, stream);
  colmean<<<dim3(64, 2), 256, 0, stream>>>(xb, means);
  final_k<<<1, 256, 0, stream>>>(means, dw, db, outp);
}

// Round 17
// 937.033 us; speedup vs baseline: 1.0120x; 1.0120x over previous
//
#include <hip/hip_runtime.h>

typedef __bf16 bf16_t;
typedef bf16_t bf16x8 __attribute__((ext_vector_type(8)));
typedef float f32x4 __attribute__((ext_vector_type(4)));
typedef unsigned short u16x4 __attribute__((ext_vector_type(4)));
typedef unsigned short u16x8 __attribute__((ext_vector_type(8)));
typedef float f32x4v __attribute__((ext_vector_type(4)));

#define NL 4

__device__ __forceinline__ float bf2f(unsigned short u){
  unsigned int x = ((unsigned int)u) << 16;
  return __builtin_bit_cast(float, x);
}
__device__ __forceinline__ unsigned short f2bf(float f){
  unsigned int u = __builtin_bit_cast(unsigned int, f);
  u += 0x7FFFu + ((u >> 16) & 1u);
  return (unsigned short)(u >> 16);
}
__device__ __forceinline__ void gload16(const void* g, void* l){
  __builtin_amdgcn_global_load_lds((const __attribute__((address_space(1))) unsigned int*)g,
                                   (__attribute__((address_space(3))) unsigned int*)l, 16, 0, 0);
}

// ------- fused f32->bf16 convert + 64x64 transpose (all 768x768 weight mats, z=16) ----
__global__ __launch_bounds__(256) void transpose_cvt16(const float* __restrict__ wq,
                                                       const float* __restrict__ wk,
                                                       const float* __restrict__ wv,
                                                       const float* __restrict__ wo,
                                                       unsigned short* __restrict__ wqkvT,
                                                       unsigned short* __restrict__ woT){
  __shared__ unsigned short tile[64][72];
  const int zi = blockIdx.z;
  const size_t W = (size_t)768 * 768;
  const float* src = (zi < 4 ? wq : zi < 8 ? wk : zi < 12 ? wv : wo) + (size_t)(zi & 3) * W;
  unsigned short* dst = (zi < 12 ? wqkvT + (size_t)zi * W : woT + (size_t)(zi - 12) * W);
  int tc0 = blockIdx.x * 64, tr0 = blockIdx.y * 64;
  int t = threadIdx.x;
  int r = t >> 2, cs = (t & 3) * 16;
  const float* s = src + (size_t)(tr0 + r) * 768 + tc0 + cs;
  #pragma unroll
  for (int j = 0; j < 16; j += 4){
    f32x4v v = *(const f32x4v*)(s + j);
    #pragma unroll
    for (int q = 0; q < 4; q++) tile[r][cs + j + q] = f2bf(v[q]);
  }
  __syncthreads();
  int n = t >> 2;
  unsigned short* d = dst + (size_t)(tc0 + n) * 768 + tr0 + cs;
  u16x8 o0, o1;
  #pragma unroll
  for (int j = 0; j < 8; j++){ o0[j] = tile[cs + j][n]; o1[j] = tile[cs + 8 + j][n]; }
  *(u16x8*)d       = o0;
  *(u16x8*)(d + 8) = o1;
}

// ------- generic convert+transpose for FF weights -------------------------------------
__global__ __launch_bounds__(256) void transpose_cvt(const float* __restrict__ src,
                                                     unsigned short* __restrict__ dst,
                                                     int R, int C){
  __shared__ unsigned short tile[64][72];
  size_t boff = (size_t)blockIdx.z * (size_t)R * (size_t)C;
  int tc0 = blockIdx.x * 64, tr0 = blockIdx.y * 64;
  int t = threadIdx.x;
  int r = t >> 2, cs = (t & 3) * 16;
  const float* s = src + boff + (size_t)(tr0 + r) * C + tc0 + cs;
  #pragma unroll
  for (int j = 0; j < 16; j += 4){
    f32x4v v = *(const f32x4v*)(s + j);
    #pragma unroll
    for (int q = 0; q < 4; q++) tile[r][cs + j + q] = f2bf(v[q]);
  }
  __syncthreads();
  int n = t >> 2;
  unsigned short* d = dst + boff + (size_t)(tc0 + n) * R + tr0 + cs;
  u16x8 o0, o1;
  #pragma unroll
  for (int j = 0; j < 8; j++){ o0[j] = tile[cs + j][n]; o1[j] = tile[cs + 8 + j][n]; }
  *(u16x8*)d       = o0;
  *(u16x8*)(d + 8) = o1;
}

// ------- GEMM core v5b: 128x128, BK=64, 2-buf (64 KB), reg-frags, STAGE under MFMA ----
// R13 lesson: 2 buffers is sync-minimal; >64 KB LDS = 1 block/CU = proven loss.
// R15: no setprio (negative on lockstep GEMM, m190). R16 lesson: epilogue residual
// fusion is NEGATIVE here (tail epilogue has no stall shadow to hide the read).
template<int ACT, int STORE_MODE>
__device__ __forceinline__ void gemm_core(unsigned short* lds,
                                          const unsigned short* __restrict__ A,
                                          const unsigned short* __restrict__ BT,
                                          const float* __restrict__ bias,
                                          unsigned short* __restrict__ C,
                                          int m0, int n0, int N, int K){
  const int t = threadIdx.x;
  const int lane = t & 63;
  const int l15 = lane & 15, l4 = lane >> 4;
  const int w = t >> 6, wm = w >> 1, wn = w & 1;
  f32x4 acc[4][4] = {};
  const int rr = t >> 3;
  const int c8 = ((t & 7) ^ (rr & 7)) * 8;
  const unsigned short* Abase = A  + (size_t)(m0 + rr) * K + c8;
  const unsigned short* Bbase = BT + (size_t)(n0 + rr) * K + c8;

  auto STAGE = [&](int k0, int buf){
    unsigned short* As_ = lds + buf * 16384;
    unsigned short* Bs_ = As_ + 8192;
    #pragma unroll
    for (int it = 0; it < 4; it++){
      gload16(Abase + (size_t)(it * 32) * K + k0, As_ + (it * 256 + t) * 8);
      gload16(Bbase + (size_t)(it * 32) * K + k0, Bs_ + (it * 256 + t) * 8);
    }
  };

  bf16x8 af[2][4], bfr[2][4];
  auto LOADFRAGS = [&](int buf){
    const unsigned short* Ab = lds + buf * 16384;
    const unsigned short* Bb = Ab + 8192;
    #pragma unroll
    for (int kk = 0; kk < 2; kk++){
      #pragma unroll
      for (int i = 0; i < 4; i++){
        const int so = ((kk * 4 + l4) ^ (l15 & 7)) * 8;
        af[kk][i]  = *(const bf16x8*)(Ab + (wm * 64 + i * 16 + l15) * 64 + so);
        bfr[kk][i] = *(const bf16x8*)(Bb + (wn * 64 + i * 16 + l15) * 64 + so);
      }
    }
  };
  auto MFMAS = [&](){
    #pragma unroll
    for (int kk = 0; kk < 2; kk++)
      #pragma unroll
      for (int j = 0; j < 4; j++)
        #pragma unroll
        for (int i = 0; i < 4; i++)
          acc[j][i] = __builtin_amdgcn_mfma_f32_16x16x32_bf16(bfr[kk][j], af[kk][i], acc[j][i], 0, 0, 0);
  };

  const int S = K >> 6;
  STAGE(0, 0); STAGE(64, 1);
  asm volatile("s_waitcnt vmcnt(8)" ::: "memory");
  __builtin_amdgcn_s_barrier();
  int cur = 0;
  for (int k = 0; k < S; k++){
    LOADFRAGS(cur);
    asm volatile("s_waitcnt lgkmcnt(0)" ::: "memory");
    __builtin_amdgcn_sched_barrier(0);         // rule #18: pin MFMA below the lgkm wait
    __builtin_amdgcn_s_barrier();              // all waves' frags in regs -> cur free
    if (k + 2 < S) STAGE((k + 2) << 6, cur);   // overwrite cur under the MFMAs
    MFMAS();
    if (k + 1 < S){
      if (k + 2 < S) asm volatile("s_waitcnt vmcnt(8)" ::: "memory");
      else           asm volatile("s_waitcnt vmcnt(0)" ::: "memory");
      __builtin_amdgcn_s_barrier();            // buf cur^1 staged for all waves
    }
    cur ^= 1;
  }

  const int mB = m0 + wm * 64;
  const int nB = n0 + wn * 64;
  if (STORE_MODE == 0){
    #pragma unroll
    for (int i = 0; i < 4; i++){
      unsigned short* crow = C + (size_t)(mB + i * 16 + l15) * N + nB;
      #pragma unroll
      for (int j = 0; j < 4; j++){
        const int nn = j * 16 + l4 * 4;
        f32x4v bb = *(const f32x4v*)(bias + nB + nn);
        u16x4 pk;
        #pragma unroll
        for (int r = 0; r < 4; r++){
          float v = acc[j][i][r] + bb[r];
          if (ACT == 1){
            float e = __expf(-1.5957691216057308f * (v + 0.044715f * v * v * v));
            v = __fdividef(v, 1.0f + e);
          }
          pk[r] = f2bf(v);
        }
        *(u16x4*)(crow + nn) = pk;
      }
    }
  } else {
    // V^T store: dst[(m>>12)*768*4096 + n*4096 + (m&4095)]
    #pragma unroll
    for (int i = 0; i < 4; i++){
      const int m = mB + i * 16 + l15;
      unsigned short* vbase = C + (size_t)(m >> 12) * 768 * 4096 + (m & 4095);
      #pragma unroll
      for (int j = 0; j < 4; j++){
        const int nn = nB + j * 16 + l4 * 4;
        f32x4v bb = *(const f32x4v*)(bias + nn);
        #pragma unroll
        for (int r = 0; r < 4; r++)
          vbase[(size_t)(nn + r) * 4096] = f2bf(acc[j][i][r] + bb[r]);
      }
    }
  }
}

// grid = 8 XCDs x 8 m-chunk x Nn (1D). XCD x owns m in [x*8, x*8+8) for ALL n.
template<int ACT>
__global__ __launch_bounds__(256) void gemm_bt(const unsigned short* __restrict__ A,
                                               const unsigned short* __restrict__ BT,
                                               const float* __restrict__ bias,
                                               unsigned short* __restrict__ C, int N, int K){
  __shared__ unsigned short lds[32768];
  const int b = blockIdx.x;
  const int s = b >> 3;
  const int m = (b & 7) * 8 + (s & 7);
  const int n = s >> 3;
  gemm_core<ACT, 0>(lds, A, BT, bias, C, m * 128, n * 128, N, K);
}

// fused Q/K/V projection: 1152 blocks = 8 xcd x 8 m x 18; V written transposed to vt
__global__ __launch_bounds__(256) void qkv_gemm(const unsigned short* __restrict__ A,
                                                const unsigned short* __restrict__ wT,
                                                int l,
                                                const float* __restrict__ bq,
                                                const float* __restrict__ bk,
                                                const float* __restrict__ bv,
                                                unsigned short* __restrict__ q,
                                                unsigned short* __restrict__ k,
                                                unsigned short* __restrict__ vt){
  __shared__ unsigned short lds[32768];
  const int b = blockIdx.x;
  const int s = b >> 3;
  const int m0 = ((b & 7) * 8 + (s & 7)) * 128;
  const int grp = s >> 3;
  const int sel = grp / 6, col = grp % 6;
  const unsigned short* BT = wT + ((size_t)sel * NL + l) * (size_t)(768 * 768);
  if (sel == 2)      gemm_core<0, 2>(lds, A, BT, bv, vt, m0, col * 128, 768, 768);
  else               gemm_core<0, 0>(lds, A, BT, sel == 0 ? bq : bk, sel == 0 ? q : k,
                                     m0, col * 128, 768, 768);
}

// ---------------- sliding-window attention: dbuf K/V, stage-at-top, 1 barrier/chunk ---
__global__ __launch_bounds__(256, 4) void attn_kernel(const unsigned short* __restrict__ Q,
                                                      const unsigned short* __restrict__ Km,
                                                      const unsigned short* __restrict__ VT,
                                                      const int* __restrict__ mask1,
                                                      const int* __restrict__ mask2,
                                                      unsigned short* __restrict__ O){
  const int qt = blockIdx.x, h = blockIdx.y, seq = blockIdx.z;
  const int t = threadIdx.x, lane = t & 63, w = t >> 6;
  const int l15 = lane & 15, l4 = lane >> 4;
  __shared__ unsigned short Kc[2][64 * 64];
  __shared__ unsigned short VTc[2][64 * 64];
  __shared__ unsigned short Ps[4][16 * 64];
  const unsigned short* Qp  = Q  + (size_t)seq * 4096 * 768;
  const unsigned short* Kp  = Km + (size_t)seq * 4096 * 768;
  const unsigned short* VTp = VT + (size_t)seq * 768 * 4096;
  const int* mask = seq ? mask2 : mask1;
  unsigned short* Op = O + (size_t)seq * 4096 * 768;

  const int q0 = qt * 64 + w * 16;
  const int qg = q0 + l15;
  const int swz = (l15 & 7) * 8;

  bf16x8 qf[2];
  #pragma unroll
  for (int ks = 0; ks < 2; ks++)
    qf[ks] = *(const bf16x8*)(Qp + (size_t)qg * 768 + h * 64 + ks * 32 + l4 * 8);

  f32x4 oacc[4] = {};
  float rm = -1e30f, rl = 0.0f;

  const int kstart = qt * 64 >= 256 ? qt * 64 - 256 : 0;
  const int kend0  = qt * 64 + 320;
  const int kend   = kend0 > 4096 ? 4096 : kend0;
  const int nch    = (kend - kstart) >> 6;
  unsigned short* psw = &Ps[w][0];

  const int rr = t >> 3;
  const int c8 = (((t & 7) ^ (rr & 7)) * 8);

  auto STAGE = [&](int kb, int buf){
    gload16(Kp  + (size_t)(kb + rr) * 768 + h * 64 + c8,       Kc[buf] + t * 8);
    gload16(Kp  + (size_t)(kb + 32 + rr) * 768 + h * 64 + c8,  Kc[buf] + 2048 + t * 8);
    gload16(VTp + (size_t)(h * 64 + rr) * 4096 + kb + c8,      VTc[buf] + t * 8);
    gload16(VTp + (size_t)(h * 64 + 32 + rr) * 4096 + kb + c8, VTc[buf] + 2048 + t * 8);
  };

  STAGE(kstart, 0);
  asm volatile("s_waitcnt vmcnt(0)" ::: "memory");
  __builtin_amdgcn_s_barrier();
  int cur = 0;
  for (int ci = 0; ci < nch; ci++){
    const int kb = kstart + (ci << 6);
    if (ci + 1 < nch) STAGE(kb + 64, cur ^ 1);      // prefetch under compute
    if (kb + 63 >= q0 - 256 && kb <= q0 + 271){
      f32x4 sT[4];
      #pragma unroll
      for (int mt = 0; mt < 4; mt++){
        const unsigned short* kr = Kc[cur] + (mt * 16 + l15) * 64;
        bf16x8 kf0 = *(const bf16x8*)(kr + ((l4 * 8) ^ swz));
        bf16x8 kf1 = *(const bf16x8*)(kr + ((32 + l4 * 8) ^ swz));
        f32x4 z = {};
        z      = __builtin_amdgcn_mfma_f32_16x16x32_bf16(kf0, qf[0], z, 0, 0, 0);
        sT[mt] = __builtin_amdgcn_mfma_f32_16x16x32_bf16(kf1, qf[1], z, 0, 0, 0);
      }
      float smax = -1e30f;
      #pragma unroll
      for (int mt = 0; mt < 4; mt++){
        int4 mv = *(const int4*)(mask + kb + mt * 16 + l4 * 4);
        #pragma unroll
        for (int r = 0; r < 4; r++){
          int kgl = kb + mt * 16 + l4 * 4 + r;
          int d = kgl - qg;
          int mvv = (r == 0) ? mv.x : (r == 1) ? mv.y : (r == 2) ? mv.z : mv.w;
          bool ok = (mvv != 0) && (d <= 256) && (d >= -256);
          float v = sT[mt][r] * 0.125f;
          sT[mt][r] = ok ? v : -1e30f;
          smax = fmaxf(smax, sT[mt][r]);
        }
      }
      smax = fmaxf(smax, __shfl_xor(smax, 16, 64));
      smax = fmaxf(smax, __shfl_xor(smax, 32, 64));
      float nm = fmaxf(rm, smax);
      float sc = __expf(rm - nm);
      rm = nm;
      float psum = 0.0f;
      #pragma unroll
      for (int mt = 0; mt < 4; mt++){
        u16x4 pk;
        #pragma unroll
        for (int r = 0; r < 4; r++){
          float p = (sT[mt][r] > -1e29f) ? __expf(sT[mt][r] - nm) : 0.0f;
          psum += p;
          pk[r] = f2bf(p);
        }
        *(u16x4*)(psw + l15 * 64 + ((mt * 16 + l4 * 4) ^ swz)) = pk;
      }
      psum += __shfl_xor(psum, 16, 64);
      psum += __shfl_xor(psum, 32, 64);
      rl = rl * sc + psum;
      float scq[4];
      #pragma unroll
      for (int r = 0; r < 4; r++) scq[r] = __shfl(sc, l4 * 4 + r, 64);
      #pragma unroll
      for (int g = 0; g < 4; g++)
        #pragma unroll
        for (int r = 0; r < 4; r++) oacc[g][r] *= scq[r];
      asm volatile("s_waitcnt lgkmcnt(0)" ::: "memory");
      __builtin_amdgcn_sched_barrier(0);
      bf16x8 pa0 = *(const bf16x8*)(psw + l15 * 64 + ((l4 * 8) ^ swz));
      bf16x8 pa1 = *(const bf16x8*)(psw + l15 * 64 + ((32 + l4 * 8) ^ swz));
      #pragma unroll
      for (int g = 0; g < 4; g++){
        const unsigned short* vr = VTc[cur] + (g * 16 + l15) * 64;
        bf16x8 vb0 = *(const bf16x8*)(vr + ((l4 * 8) ^ swz));
        bf16x8 vb1 = *(const bf16x8*)(vr + ((32 + l4 * 8) ^ swz));
        oacc[g] = __builtin_amdgcn_mfma_f32_16x16x32_bf16(pa0, vb0, oacc[g], 0, 0, 0);
        oacc[g] = __builtin_amdgcn_mfma_f32_16x16x32_bf16(pa1, vb1, oacc[g], 0, 0, 0);
      }
    }
    asm volatile("s_waitcnt vmcnt(0)" ::: "memory");   // next chunk staged
    __builtin_amdgcn_s_barrier();                      // single barrier per chunk
    cur ^= 1;
  }
  float rlq[4];
  #pragma unroll
  for (int r = 0; r < 4; r++) rlq[r] = __shfl(rl, l4 * 4 + r, 64);
  #pragma unroll
  for (int g = 0; g < 4; g++)
    #pragma unroll
    for (int r = 0; r < 4; r++){
      float v = oacc[g][r] / rlq[r];
      Op[(size_t)(q0 + l4 * 4 + r) * 768 + h * 64 + g * 16 + l15] = f2bf(v);
    }
}

// ---------------- embed + LN (f32 tables -> bf16 out) --------------------------------
__global__ __launch_bounds__(192) void embed_ln(const int* __restrict__ ids1,
                                                const int* __restrict__ ids2,
                                                const float* __restrict__ we,
                                                const float* __restrict__ pe,
                                                const float* __restrict__ g,
                                                const float* __restrict__ b,
                                                unsigned short* __restrict__ out){
  const int row = blockIdx.x;
  const int seq = row >> 12, s = row & 4095;
  const int t = threadIdx.x;
  const int id = (seq ? ids2 : ids1)[s];
  f32x4v wvv = *(const f32x4v*)(we + (size_t)id * 768 + t * 4);
  f32x4v pv  = *(const f32x4v*)(pe + (size_t)s * 768 + t * 4);
  float v[4];
  #pragma unroll
  for (int j = 0; j < 4; j++) v[j] = wvv[j] + pv[j];
  float sum = 0, ss = 0;
  #pragma unroll
  for (int j = 0; j < 4; j++){ sum += v[j]; ss += v[j] * v[j]; }
  for (int off = 1; off < 64; off <<= 1){ sum += __shfl_xor(sum, off, 64); ss += __shfl_xor(ss, off, 64); }
  __shared__ float red[2][3];
  int wid = t >> 6;
  if ((t & 63) == 0){ red[0][wid] = sum; red[1][wid] = ss; }
  __syncthreads();
  sum = red[0][0] + red[0][1] + red[0][2];
  ss  = red[1][0] + red[1][1] + red[1][2];
  float mean = sum * (1.0f / 768.0f);
  float var  = ss * (1.0f / 768.0f) - mean * mean;
  float rstd = rsqrtf(var + 1e-5f);
  f32x4v gv = *(const f32x4v*)(g + t * 4);
  f32x4v bv = *(const f32x4v*)(b + t * 4);
  u16x4 o;
  #pragma unroll
  for (int j = 0; j < 4; j++) o[j] = f2bf((v[j] - mean) * rstd * gv[j] + bv[j]);
  *(u16x4*)(out + (size_t)row * 768 + t * 4) = o;
}

// ---------------- (A + B) -> LayerNorm -----------------------------------------------
__global__ __launch_bounds__(192) void add_ln(const unsigned short* __restrict__ A,
                                              const unsigned short* __restrict__ Bp,
                                              const float* __restrict__ g,
                                              const float* __restrict__ b,
                                              unsigned short* __restrict__ out){
  const int row = blockIdx.x;
  const int t = threadIdx.x;
  u16x4 a4 = *(const u16x4*)(A  + (size_t)row * 768 + t * 4);
  u16x4 b4 = *(const u16x4*)(Bp + (size_t)row * 768 + t * 4);
  float v[4];
  #pragma unroll
  for (int j = 0; j < 4; j++) v[j] = bf2f(a4[j]) + bf2f(b4[j]);
  float sum = 0, ss = 0;
  #pragma unroll
  for (int j = 0; j < 4; j++){ sum += v[j]; ss += v[j] * v[j]; }
  for (int off = 1; off < 64; off <<= 1){ sum += __shfl_xor(sum, off, 64); ss += __shfl_xor(ss, off, 64); }
  __shared__ float red[2][3];
  int wid = t >> 6;
  if ((t & 63) == 0){ red[0][wid] = sum; red[1][wid] = ss; }
  __syncthreads();
  sum = red[0][0] + red[0][1] + red[0][2];
  ss  = red[1][0] + red[1][1] + red[1][2];
  float mean = sum * (1.0f / 768.0f);
  float var  = ss * (1.0f / 768.0f) - mean * mean;
  float rstd = rsqrtf(var + 1e-5f);
  f32x4v gv = *(const f32x4v*)(g + t * 4);
  f32x4v bv = *(const f32x4v*)(b + t * 4);
  u16x4 o;
  #pragma unroll
  for (int j = 0; j < 4; j++) o[j] = f2bf((v[j] - mean) * rstd * gv[j] + bv[j]);
  *(u16x4*)(out + (size_t)row * 768 + t * 4) = o;
}

// ---------------- column sums ---------------------------------------------------------
__global__ __launch_bounds__(256) void colmean(const unsigned short* __restrict__ X,
                                               float* __restrict__ mean){
  const int t = threadIdx.x;
  const int seq = blockIdx.y;
  const int r0 = blockIdx.x * 64;
  const unsigned short* base = X + ((size_t)seq * 4096 + r0) * 768;
  float a0 = 0, a1 = 0, a2 = 0;
  for (int r = 0; r < 64; r++){
    const unsigned short* p = base + (size_t)r * 768;
    a0 += bf2f(p[t]);
    a1 += bf2f(p[t + 256]);
    a2 += bf2f(p[t + 512]);
  }
  atomicAdd(&mean[seq * 768 + t], a0);
  atomicAdd(&mean[seq * 768 + t + 256], a1);
  atomicAdd(&mean[seq * 768 + t + 512], a2);
}

// ---------------- final dot + sigmoid (f32 out) ---------------------------------------
__global__ __launch_bounds__(256) void final_k(const float* __restrict__ means,
                                               const float* __restrict__ dw,
                                               const float* __restrict__ db,
                                               float* __restrict__ out){
  const int t = threadIdx.x;
  float part = 0;
  for (int c = t; c < 768; c += 256)
    part += (means[c] - means[768 + c]) * (1.0f / 4096.0f) * dw[c];
  for (int off = 1; off < 64; off <<= 1) part += __shfl_xor(part, off, 64);
  __shared__ float red[4];
  if ((t & 63) == 0) red[t >> 6] = part;
  __syncthreads();
  if (t == 0){
    float r = red[0] + red[1] + red[2] + red[3] + db[0];
    out[0] = 1.0f / (1.0f + expf(-r));
  }
}

// sentinel: written when workspace is too small, to make that failure diagnosable
__global__ void sentinel_k(float* out){ out[0] = -1.0f; }

extern "C" void kernel_launch(void* const* d_in, const int* in_sizes, int n_in,
                              void* d_out, int out_size, void* d_ws, size_t ws_size,
                              hipStream_t stream){
  (void)in_sizes; (void)n_in; (void)out_size;
  const int* ids1  = (const int*)d_in[0];
  const int* ids2  = (const int*)d_in[1];
  const int* mask1 = (const int*)d_in[2];
  const int* mask2 = (const int*)d_in[3];
  const float* we = (const float*)d_in[4];
  const float* pe = (const float*)d_in[5];
  const float* eg = (const float*)d_in[6];
  const float* eb = (const float*)d_in[7];
  const float* wq = (const float*)d_in[8];
  const float* bq = (const float*)d_in[9];
  const float* wk = (const float*)d_in[10];
  const float* bk = (const float*)d_in[11];
  const float* wv = (const float*)d_in[12];
  const float* bv = (const float*)d_in[13];
  const float* wo = (const float*)d_in[14];
  const float* bo = (const float*)d_in[15];
  const float* g1 = (const float*)d_in[16];
  const float* b1 = (const float*)d_in[17];
  const float* w1 = (const float*)d_in[18];
  const float* c1 = (const float*)d_in[19];
  const float* w2 = (const float*)d_in[20];
  const float* c2 = (const float*)d_in[21];
  const float* g2 = (const float*)d_in[22];
  const float* b2 = (const float*)d_in[23];
  const float* dw = (const float*)d_in[24];
  const float* db = (const float*)d_in[25];
  float* outp = (float*)d_out;

  char* ws = (char*)d_ws;
  size_t off = 0;
  auto alloc = [&](size_t bytes) -> char* {
    char* p = ws + off;
    off += (bytes + 255) & ~(size_t)255;
    return p;
  };
  const size_t W768 = (size_t)768 * 768;
  const size_t WFF  = (size_t)768 * 3072;
  unsigned short* wqkvT = (unsigned short*)alloc(3 * NL * W768 * 2);
  unsigned short* woT   = (unsigned short*)alloc(NL * W768 * 2);
  unsigned short* w1T   = (unsigned short*)alloc(NL * WFF * 2);
  unsigned short* w2T   = (unsigned short*)alloc(NL * WFF * 2);
  unsigned short* xb    = (unsigned short*)alloc((size_t)8192 * 768 * 2);
  unsigned short* qb_   = (unsigned short*)alloc((size_t)8192 * 768 * 2);
  unsigned short* kb_   = (unsigned short*)alloc((size_t)8192 * 768 * 2);
  unsigned short* vb_   = (unsigned short*)alloc((size_t)8192 * 768 * 2);
  unsigned short* hb    = (unsigned short*)alloc((size_t)8192 * 3072 * 2);
  unsigned short* vt    = (unsigned short*)alloc((size_t)2 * 768 * 4096 * 2);
  float* means          = (float*)alloc(2 * 768 * 4);
  if (off > ws_size){ sentinel_k<<<1, 1, 0, stream>>>(outp); return; }

  transpose_cvt16<<<dim3(12, 12, 16), 256, 0, stream>>>(wq, wk, wv, wo, wqkvT, woT);
  transpose_cvt<<<dim3(48, 12, NL), 256, 0, stream>>>(w1, w1T, 768, 3072);
  transpose_cvt<<<dim3(12, 48, NL), 256, 0, stream>>>(w2, w2T, 3072, 768);

  embed_ln<<<8192, 192, 0, stream>>>(ids1, ids2, we, pe, eg, eb, xb);

  for (int l = 0; l < NL; l++){
    qkv_gemm<<<1152, 256, 0, stream>>>(xb, wqkvT, l, bq + l * 768, bk + l * 768, bv + l * 768,
                                       qb_, kb_, vt);
    attn_kernel<<<dim3(64, 12, 2), 256, 0, stream>>>(qb_, kb_, vt, mask1, mask2, vb_);
    gemm_bt<0><<<384, 256, 0, stream>>>(vb_, woT + (size_t)l * W768, bo + l * 768, qb_, 768, 768);
    add_ln<<<8192, 192, 0, stream>>>(xb, qb_, g1 + l * 768, b1 + l * 768, kb_);
    gemm_bt<1><<<1536, 256, 0, stream>>>(kb_, w1T + (size_t)l * WFF, c1 + l * 3072, hb, 3072, 768);
    gemm_bt<0><<<384, 256, 0, stream>>>(hb, w2T + (size_t)l * WFF, c2 + l * 768, vb_, 768, 3072);
    add_ln<<<8192, 192, 0, stream>>>(kb_, vb_, g2 + l * 768, b2 + l * 768, xb);
  }

  hipMemsetAsync(means, 0, 2 * 768 * 4, stream);
  colmean<<<dim3(64, 2), 256, 0, stream>>>(xb, means);
  final_k<<<1, 256, 0, stream>>>(means, dw, db, outp);
}